// Round 1
// baseline (10683.427 us; speedup 1.0000x reference)
//
#include <hip/hip_runtime.h>
#include <hip/hip_fp16.h>

#define VOCAB 32000
#define EMB   32
#define HID   256
#define BATCH 64
#define TT    2048
#define KDIM  (EMB + HID)   // 288
#define KK    (KDIM / 2)    // 144 half2 pairs along K
#define NG    (4 * HID)     // 1024 gate rows

typedef _Float16 half2_t __attribute__((ext_vector_type(2)));
typedef _Float16 half8_t __attribute__((ext_vector_type(8)));

// ws layout:
//   [0, WT_BYTES)            : half8 Wt[kk][n], kk in [0,144), n in [0,256)
//                              entry = {W(n,2kk),W(n,2kk+1), W(n+256,..), W(n+512,..), W(n+768,..)}
//                              where W(row,k) = k<32 ? W_ih[row][k] : W_hh[row][k-32]
//   [WT_BYTES, +4096)        : float bias[1024] = b_ih + b_hh
#define WT_BYTES (KK * 256 * 16)   // 589824
#define BIAS_OFF WT_BYTES

__device__ __forceinline__ float fdot2(half2_t a, half2_t b, float c) {
#if __has_builtin(__builtin_amdgcn_fdot2)
    return __builtin_amdgcn_fdot2(a, b, c, false);
#else
    return c + (float)a[0] * (float)b[0] + (float)a[1] * (float)b[1];
#endif
}

__device__ __forceinline__ float sigmoid_fast(float v) {
    return 1.0f / (1.0f + __expf(-v));
}

__device__ __forceinline__ float tanh_fast(float v) {
    // gates/c are small here (|v| < ~4), no overflow concern
    float e = __expf(2.0f * v);
    return (e - 1.0f) / (e + 1.0f);
}

// ---- prep: transpose+convert weights to K-major fp16, combine biases ----
__global__ void prep_kernel(const float* __restrict__ W_ih,
                            const float* __restrict__ W_hh,
                            const float* __restrict__ b_ih,
                            const float* __restrict__ b_hh,
                            void* __restrict__ ws) {
    int bid = blockIdx.x;
    int tid = threadIdx.x;
    if (bid < KK) {
        int kk = bid, n = tid;
        int k0 = 2 * kk;
        half8_t v;
#pragma unroll
        for (int j = 0; j < 4; ++j) {
            int row = n + 256 * j;
            float a, b;
            if (k0 < EMB) {
                a = W_ih[row * EMB + k0];
                b = W_ih[row * EMB + k0 + 1];
            } else {
                a = W_hh[row * HID + (k0 - EMB)];
                b = W_hh[row * HID + (k0 - EMB) + 1];
            }
            v[2 * j]     = (_Float16)a;
            v[2 * j + 1] = (_Float16)b;
        }
        ((half8_t*)ws)[kk * 256 + n] = v;
    } else {
        float* bias = (float*)((char*)ws + BIAS_OFF);
#pragma unroll
        for (int j = 0; j < 4; ++j) {
            int g = tid + 256 * j;
            bias[g] = b_ih[g] + b_hh[g];
        }
    }
}

// ---- recurrent kernel: one block per batch element ----
// thread n owns gate rows {n, n+256, n+512, n+768} = (i,f,g,o) for h-index n,
// so the c/h update is thread-local; h is broadcast to the block via LDS.
__global__ __launch_bounds__(256) void rnn_kernel(const int* __restrict__ x,
                                                  const int* __restrict__ lengths,
                                                  const float* __restrict__ emb,
                                                  const void* __restrict__ ws,
                                                  float* __restrict__ out) {
    const int b = blockIdx.x;
    const int n = threadIdx.x;
    const half8_t* __restrict__ wt = (const half8_t*)ws;
    const float* __restrict__ bias = (const float*)((const char*)ws + BIAS_OFF);

    __shared__ _Float16 xh[KDIM];  // [0,32): x_t part; [32,288): h part

    const float bi = bias[n];
    const float bf = bias[n + 256];
    const float bg = bias[n + 512];
    const float bo = bias[n + 768];

    float h = 0.0f, c = 0.0f;
    _Float16 hn = (_Float16)0.0f;

    int L = lengths[b];
    if (L > TT) L = TT;
    const int* __restrict__ xb = x + b * TT;

    for (int t = 0; t < L; ++t) {
        int tok = xb[t];  // wave-uniform -> scalar load
        __syncthreads();  // all reads of previous step's xh are done
        if (n < EMB) xh[n] = (_Float16)emb[tok * EMB + n];
        xh[EMB + n] = hn;
        __syncthreads();  // xh ready

        float ai = 0.0f, af = 0.0f, ag = 0.0f, ao = 0.0f;
        const half2_t* xh2 = (const half2_t*)xh;

        for (int kc = 0; kc < KK; kc += 16) {
            half8_t w[16];
#pragma unroll
            for (int u = 0; u < 16; ++u)
                w[u] = wt[(kc + u) * 256 + n];  // lane-consecutive 16B -> dwordx4
#pragma unroll
            for (int u = 0; u < 16; ++u) {
                half2_t hh = xh2[kc + u];  // LDS broadcast (same addr all lanes)
                half2_t wi = {w[u][0], w[u][1]};
                half2_t wf = {w[u][2], w[u][3]};
                half2_t wg = {w[u][4], w[u][5]};
                half2_t wo = {w[u][6], w[u][7]};
                ai = fdot2(wi, hh, ai);
                af = fdot2(wf, hh, af);
                ag = fdot2(wg, hh, ag);
                ao = fdot2(wo, hh, ao);
            }
        }

        float ig = sigmoid_fast(ai + bi);
        float fg = sigmoid_fast(af + bf);
        float gg = tanh_fast(ag + bg);
        float og = sigmoid_fast(ao + bo);
        c = fg * c + ig * gg;
        h = og * tanh_fast(c);
        hn = (_Float16)h;  // fp16 h feeds next step's dot products
    }

    out[b * HID + n] = h;  // (B,1,HID) flat
}

extern "C" void kernel_launch(void* const* d_in, const int* in_sizes, int n_in,
                              void* d_out, int out_size, void* d_ws, size_t ws_size,
                              hipStream_t stream) {
    const int*   x       = (const int*)d_in[0];
    const int*   lengths = (const int*)d_in[1];
    const float* emb     = (const float*)d_in[2];
    const float* W_ih    = (const float*)d_in[3];
    const float* W_hh    = (const float*)d_in[4];
    const float* b_ih    = (const float*)d_in[5];
    const float* b_hh    = (const float*)d_in[6];
    float* out = (float*)d_out;

    // prep: 144 weight blocks + 1 bias block
    prep_kernel<<<KK + 1, 256, 0, stream>>>(W_ih, W_hh, b_ih, b_hh, d_ws);
    // recurrence: one block per batch element
    rnn_kernel<<<BATCH, 256, 0, stream>>>(x, lengths, emb, d_ws, out);
}

// Round 2
// 4429.507 us; speedup vs baseline: 2.4119x; 2.4119x over previous
//
#include <hip/hip_runtime.h>
#include <hip/hip_fp16.h>

#define VOCAB 32000
#define EMB   32
#define HID   256
#define BATCH 64
#define TT    2048
#define KD    288            // EMB + HID

typedef _Float16 half2_t __attribute__((ext_vector_type(2)));
typedef _Float16 half8_t __attribute__((ext_vector_type(8)));

// ---- ws regions (bytes) ----
// X: x-part weights, cols 0..31, streamed each step.  layout half8[j][row], j in [0,4)
// V: VGPR-resident cols 32..223.                      layout half8[j][row], j in [0,24)
// L: LDS image, cols 224..287, pre-padded rows.       layout [row][72 halves] (144 B rows)
// B: combined bias, 1024 floats
#define X_OFF   0
#define V_OFF   65536        // 4*1024*16
#define L_OFF   458752       // V_OFF + 24*1024*16
#define B_OFF   606208       // L_OFF + 1024*144
#define WS_TOTAL 610304

// ---- dynamic LDS layout ----
#define LDS_XH  147456       // weight image occupies [0,147456)
#define LDS_GB  148096       // xh: 320 halves (288 used)
#define LDS_TOTAL 150144     // gbuf: 512 floats

__device__ __forceinline__ float fdot2(half2_t a, half2_t b, float c) {
#if __has_builtin(__builtin_amdgcn_fdot2)
    return __builtin_amdgcn_fdot2(a, b, c, false);
#else
    return c + (float)a[0] * (float)b[0] + (float)a[1] * (float)b[1];
#endif
}

__device__ __forceinline__ float dot8(half8_t w, half8_t x, float acc) {
    acc = fdot2(half2_t{w[0], w[1]}, half2_t{x[0], x[1]}, acc);
    acc = fdot2(half2_t{w[2], w[3]}, half2_t{x[2], x[3]}, acc);
    acc = fdot2(half2_t{w[4], w[5]}, half2_t{x[4], x[5]}, acc);
    acc = fdot2(half2_t{w[6], w[7]}, half2_t{x[6], x[7]}, acc);
    return acc;
}

__device__ __forceinline__ float sigmoid_fast(float v) {
    return 1.0f / (1.0f + __expf(-v));
}
__device__ __forceinline__ float tanh_fast(float v) {
    v = fminf(fmaxf(v, -20.0f), 20.0f);   // avoid exp overflow -> NaN
    float e = __expf(2.0f * v);
    return (e - 1.0f) / (e + 1.0f);
}

// ---- prep: scatter weights into X/V/L layouts (fp16), combine biases ----
// grid: 1040 blocks x 64 threads. blocks [0,1024) = one row each; [1024,1040) = bias.
// col k in [0,288): k<32 -> W_ih[row][k] ; else W_hh[row][k-32]
__global__ void prep_kernel(const float* __restrict__ W_ih,
                            const float* __restrict__ W_hh,
                            const float* __restrict__ b_ih,
                            const float* __restrict__ b_hh,
                            char* __restrict__ ws) {
    int bid = blockIdx.x, t = threadIdx.x;
    if (bid < 1024) {
        int row = bid;
        if (t < 4) {                         // X chunk t: cols 8t..8t+7 (all W_ih)
            half8_t v;
#pragma unroll
            for (int q = 0; q < 8; ++q) v[q] = (_Float16)W_ih[row * EMB + 8 * t + q];
            *(half8_t*)(ws + X_OFF + (size_t)(t * 1024 + row) * 16) = v;
        } else if (t < 28) {                 // V chunk j=t-4: cols 32+8j.. -> W_hh cols 8j..
            int j = t - 4;
            half8_t v;
#pragma unroll
            for (int q = 0; q < 8; ++q) v[q] = (_Float16)W_hh[row * HID + 8 * j + q];
            *(half8_t*)(ws + V_OFF + (size_t)(j * 1024 + row) * 16) = v;
        } else if (t < 37) {                 // L sub-chunk u=t-28: halves 8u..8u+7 of 72
            int u = t - 28;
            half8_t v;
#pragma unroll
            for (int q = 0; q < 8; ++q) {
                int cc = 8 * u + q;          // col 224+cc -> W_hh col 192+cc
                v[q] = (cc < 64) ? (_Float16)W_hh[row * HID + 192 + cc] : (_Float16)0.0f;
            }
            *(half8_t*)(ws + L_OFF + (size_t)row * 144 + u * 16) = v;
        }
    } else {
        int g = (bid - 1024) * 64 + t;       // bias
        ((float*)(ws + B_OFF))[g] = b_ih[g] + b_hh[g];
    }
}

// ---- recurrent kernel: one block (512 threads) per batch element ----
// thread t owns gate rows r0=t, r1=t+512:
//   t<256:  r0 = i-row t,      r1 = g-row (t+512)
//   t>=256: r0 = f-row t,      r1 = o-row (t+512)
// c/h update done by threads <256 after an f,o exchange through LDS gbuf.
__global__ __launch_bounds__(512, 2) void rnn_kernel(const int* __restrict__ x,
                                                     const int* __restrict__ lengths,
                                                     const float* __restrict__ emb,
                                                     const char* __restrict__ ws,
                                                     float* __restrict__ out) {
    extern __shared__ char smem[];
    _Float16* xh  = (_Float16*)(smem + LDS_XH);   // [0,32): x_t, [32,288): h
    float*    gbuf = (float*)(smem + LDS_GB);

    const int b   = blockIdx.x;
    const int tid = threadIdx.x;
    const int r0  = tid;
    const int r1  = tid + 512;

    // stage LDS weight image (cols 224..287, pre-padded rows of 144 B)
    {
        const uint4* src = (const uint4*)(ws + L_OFF);
        uint4*       dst = (uint4*)smem;
#pragma unroll
        for (int k = 0; k < 18; ++k) dst[tid + k * 512] = src[tid + k * 512];
    }

    // VGPR-resident weights: cols 32..223 of rows r0, r1 (24 chunks x 8 cols)
    half8_t wv0[24], wv1[24];
    {
        const half8_t* V = (const half8_t*)(ws + V_OFF);
#pragma unroll
        for (int j = 0; j < 24; ++j) {
            wv0[j] = V[j * 1024 + r0];
            wv1[j] = V[j * 1024 + r1];
        }
    }

    const float* biasp = (const float*)(ws + B_OFF);
    float bi = 0.f, bf = 0.f, bg = 0.f, bo = 0.f;
    if (tid < HID) {
        bi = biasp[tid];
        bf = biasp[tid + 256];
        bg = biasp[tid + 512];
        bo = biasp[tid + 768];
    }

    int L = lengths[b];
    if (L > TT) L = TT;
    if (L < 0) L = 0;
    const int* __restrict__ xb = x + b * TT;

    // init xh: x-part = emb[token 0], h-part = 0
    if (tid < HID) xh[EMB + tid] = (_Float16)0.0f;
    if (tid < EMB) xh[tid] = (_Float16)emb[xb[0] * EMB + tid];
    float c = 0.0f, h = 0.0f;
    __syncthreads();

    const half8_t* Xr = (const half8_t*)(ws + X_OFF);

#pragma unroll 1
    for (int t = 0; t < L; ++t) {
        // prefetch next token's embedding (threads 256..287) — long latency, issue first
        float ev = 0.0f;
        if (tid >= 256 && tid < 256 + EMB) {
            int nt = (t + 1 < L) ? xb[t + 1] : 0;
            ev = emb[nt * EMB + (tid - 256)];
        }

        float a0 = 0.0f, a1 = 0.0f;

        // VGPR-part dots, first half (hides nothing yet, keeps pressure low)
#pragma unroll
        for (int j = 0; j < 12; ++j) {
            half8_t xv = *(const half8_t*)(xh + EMB + 8 * j);
            a0 = dot8(wv0[j], xv, a0);
            a1 = dot8(wv1[j], xv, a1);
        }

        // issue x-part weight loads (64 KB region, L1/L2-resident)
        half8_t xs0[4], xs1[4];
#pragma unroll
        for (int j = 0; j < 4; ++j) {
            xs0[j] = Xr[j * 1024 + r0];
            xs1[j] = Xr[j * 1024 + r1];
        }

        // VGPR-part dots, second half (covers the x-part load latency)
#pragma unroll
        for (int j = 12; j < 24; ++j) {
            half8_t xv = *(const half8_t*)(xh + EMB + 8 * j);
            a0 = dot8(wv0[j], xv, a0);
            a1 = dot8(wv1[j], xv, a1);
        }

        // x-part dots (cols 0..31)
#pragma unroll
        for (int j = 0; j < 4; ++j) {
            half8_t xv = *(const half8_t*)(xh + 8 * j);
            a0 = dot8(xs0[j], xv, a0);
            a1 = dot8(xs1[j], xv, a1);
        }

        // LDS-part dots (cols 224..287); row stride 144 B -> conflict-free b128
#pragma unroll
        for (int j = 0; j < 8; ++j) {
            half8_t xv = *(const half8_t*)(xh + 224 + 8 * j);
            half8_t w0 = *(const half8_t*)(smem + r0 * 144 + j * 16);
            half8_t w1 = *(const half8_t*)(smem + r1 * 144 + j * 16);
            a0 = dot8(w0, xv, a0);
            a1 = dot8(w1, xv, a1);
        }

        // exchange f,o pre-activations
        if (tid >= 256) {
            gbuf[tid - 256] = a0;   // f for h-index tid-256
            gbuf[tid]       = a1;   // o for h-index tid-256
        }
        __syncthreads();

        if (tid < 256) {
            float iv = sigmoid_fast(a0 + bi);
            float gv = tanh_fast(a1 + bg);
            float fv = sigmoid_fast(gbuf[tid] + bf);
            float ov = sigmoid_fast(gbuf[tid + 256] + bo);
            c = fv * c + iv * gv;
            h = ov * tanh_fast(c);
            xh[EMB + tid] = (_Float16)h;
        } else if (tid < 256 + EMB) {
            xh[tid - 256] = (_Float16)ev;   // x-part for step t+1
        }
        __syncthreads();
    }

    if (tid < HID) out[b * HID + tid] = h;
}

extern "C" void kernel_launch(void* const* d_in, const int* in_sizes, int n_in,
                              void* d_out, int out_size, void* d_ws, size_t ws_size,
                              hipStream_t stream) {
    const int*   x       = (const int*)d_in[0];
    const int*   lengths = (const int*)d_in[1];
    const float* emb     = (const float*)d_in[2];
    const float* W_ih    = (const float*)d_in[3];
    const float* W_hh    = (const float*)d_in[4];
    const float* b_ih    = (const float*)d_in[5];
    const float* b_hh    = (const float*)d_in[6];
    float* out = (float*)d_out;
    char*  ws  = (char*)d_ws;

    static int attr_set = 0;
    (void)attr_set;
    hipFuncSetAttribute(reinterpret_cast<const void*>(rnn_kernel),
                        hipFuncAttributeMaxDynamicSharedMemorySize, LDS_TOTAL);

    prep_kernel<<<1040, 64, 0, stream>>>(W_ih, W_hh, b_ih, b_hh, ws);
    rnn_kernel<<<BATCH, 512, LDS_TOTAL, stream>>>(x, lengths, emb, ws, out);
}